// Round 2
// baseline (111.165 us; speedup 1.0000x reference)
//
#include <hip/hip_runtime.h>
#include <hip/hip_bf16.h>

typedef __attribute__((ext_vector_type(8))) __bf16 bf16x8;
typedef __attribute__((ext_vector_type(4))) float  f32x4;

constexpr int NN = 2048;   // points per batch
constexpr int DD = 128;    // dim
constexpr int TS = 65;     // LDS transpose row stride (odd -> conflict-light b32 readback)

// ---- pre-pass: sq[b*NN+n] = sum_d bf16(x[b,n,d])^2  (fp32 accumulate) ----
__global__ __launch_bounds__(256, 4)
void sq_kernel(const float* __restrict__ x, float* __restrict__ sq) {
    const int lane = threadIdx.x & 63;
    const int row  = blockIdx.x * 4 + (threadIdx.x >> 6);   // 0..8191
    const float2 v = *(const float2*)(x + (size_t)row * DD + lane * 2);
    const float f0 = (float)(__bf16)v.x;
    const float f1 = (float)(__bf16)v.y;
    float s = f0 * f0 + f1 * f1;
    #pragma unroll
    for (int m = 1; m < 64; m <<= 1) s += __shfl_xor(s, m, 64);
    if (lane == 0) sq[row] = s;
}

// ---- main: one block = 128x128 tile, one wave = 64x64, no barriers ----
__global__ __launch_bounds__(256, 3)
void edm_main(const float* __restrict__ x, const float* __restrict__ sq,
              float* __restrict__ out) {
    __shared__ float tile[4][32 * TS];   // per-wave transpose buffer (8320 B each)

    const int t    = threadIdx.x;
    const int wave = t >> 6;
    const int lane = t & 63;
    const int lm   = lane & 15;
    const int q    = lane >> 4;

    const int jt = blockIdx.x;   // 0..15
    const int it = blockIdx.y;   // 0..15
    const int b  = blockIdx.z;   // 0..3

    const int i0 = it * 128 + (wave >> 1) * 64;
    const int j0 = jt * 128 + (wave & 1) * 64;

    const float* xb  = x  + (size_t)b * NN * DD;
    const float* sqb = sq + (size_t)b * NN;

    f32x4 acc[4][4] = {};

    #pragma unroll
    for (int ks = 0; ks < 4; ++ks) {
        const int kb = ks * 32 + q * 8;
        bf16x8 a[4], bb[4];
        #pragma unroll
        for (int mf = 0; mf < 4; ++mf) {
            const float4* p = (const float4*)(xb + (size_t)(i0 + mf * 16 + lm) * DD + kb);
            const float4 v0 = p[0];
            const float4 v1 = p[1];
            bf16x8 w;
            w[0] = (__bf16)v0.x; w[1] = (__bf16)v0.y;
            w[2] = (__bf16)v0.z; w[3] = (__bf16)v0.w;
            w[4] = (__bf16)v1.x; w[5] = (__bf16)v1.y;
            w[6] = (__bf16)v1.z; w[7] = (__bf16)v1.w;
            a[mf] = w;
        }
        #pragma unroll
        for (int nf = 0; nf < 4; ++nf) {
            const float4* p = (const float4*)(xb + (size_t)(j0 + nf * 16 + lm) * DD + kb);
            const float4 v0 = p[0];
            const float4 v1 = p[1];
            bf16x8 w;
            w[0] = (__bf16)v0.x; w[1] = (__bf16)v0.y;
            w[2] = (__bf16)v0.z; w[3] = (__bf16)v0.w;
            w[4] = (__bf16)v1.x; w[5] = (__bf16)v1.y;
            w[6] = (__bf16)v1.z; w[7] = (__bf16)v1.w;
            bb[nf] = w;
        }
        #pragma unroll
        for (int mf = 0; mf < 4; ++mf)
            #pragma unroll
            for (int nf = 0; nf < 4; ++nf)
                acc[mf][nf] = __builtin_amdgcn_mfma_f32_16x16x32_bf16(
                    a[mf], bb[nf], acc[mf][nf], 0, 0, 0);
    }

    // squared norms
    f32x4 sqi[4];
    float sqj[4];
    #pragma unroll
    for (int mf = 0; mf < 4; ++mf)
        sqi[mf] = *(const f32x4*)(sqb + i0 + mf * 16 + q * 4);
    #pragma unroll
    for (int nf = 0; nf < 4; ++nf)
        sqj[nf] = sqb[j0 + nf * 16 + lm];

    // epilogue: sqrt(max(sqi+sqj-2c,0)+eps), transposed through per-wave LDS,
    // stored as coalesced dwordx4. Two halves of 32 rows each.
    float* tl = tile[wave];
    #pragma unroll
    for (int h = 0; h < 2; ++h) {
        #pragma unroll
        for (int mf2 = 0; mf2 < 2; ++mf2) {
            const int mf = h * 2 + mf2;
            #pragma unroll
            for (int nf = 0; nf < 4; ++nf) {
                #pragma unroll
                for (int r = 0; r < 4; ++r) {
                    float d2 = sqi[mf][r] + sqj[nf] - 2.0f * acc[mf][nf][r];
                    d2 = fmaxf(d2, 0.0f);
                    tl[(mf2 * 16 + q * 4 + r) * TS + nf * 16 + lm] = sqrtf(d2 + 1e-7f);
                }
            }
        }
        #pragma unroll
        for (int iter = 0; iter < 8; ++iter) {
            const int rr = iter * 4 + q;   // 0..31
            f32x4 v;
            #pragma unroll
            for (int d = 0; d < 4; ++d) v[d] = tl[rr * TS + lm * 4 + d];
            *(f32x4*)(out + ((size_t)b * NN + i0 + h * 32 + rr) * NN + j0 + lm * 4) = v;
        }
    }
}

extern "C" void kernel_launch(void* const* d_in, const int* in_sizes, int n_in,
                              void* d_out, int out_size, void* d_ws, size_t ws_size,
                              hipStream_t stream) {
    const float* x = (const float*)d_in[0];
    float* out = (float*)d_out;
    float* sq  = (float*)d_ws;   // 4*2048 floats = 32 KB scratch

    sq_kernel<<<dim3(4 * NN / 4), dim3(256), 0, stream>>>(x, sq);
    edm_main<<<dim3(16, 16, 4), dim3(256), 0, stream>>>(x, sq, out);
}

// Round 3
// 87.727 us; speedup vs baseline: 1.2672x; 1.2672x over previous
//
#include <hip/hip_runtime.h>
#include <hip/hip_bf16.h>

typedef __attribute__((ext_vector_type(8))) __bf16 bf16x8;
typedef __attribute__((ext_vector_type(2))) __bf16 bf16x2;
typedef __attribute__((ext_vector_type(4))) float  f32x4;

constexpr int NN = 2048;   // points per batch
constexpr int DD = 128;    // dim

// ---- pre-pass: bf16-convert x into ws and compute sq from the ROUNDED values
__global__ __launch_bounds__(256, 4)
void prep_kernel(const float* __restrict__ x, __bf16* __restrict__ xb,
                 float* __restrict__ sq) {
    const int lane = threadIdx.x & 63;
    const int row  = blockIdx.x * 4 + (threadIdx.x >> 6);   // 0..8191
    const float2 v = *(const float2*)(x + (size_t)row * DD + lane * 2);
    const __bf16 b0 = (__bf16)v.x;
    const __bf16 b1 = (__bf16)v.y;
    bf16x2 w; w[0] = b0; w[1] = b1;
    *(bf16x2*)(xb + (size_t)row * DD + lane * 2) = w;
    const float f0 = (float)b0, f1 = (float)b1;
    float s = f0 * f0 + f1 * f1;
    #pragma unroll
    for (int m = 1; m < 64; m <<= 1) s += __shfl_xor(s, m, 64);
    if (lane == 0) sq[row] = s;
}

// ---- main: 128x128 tile per block, XOR-swizzled LDS, one barrier ----
__global__ __launch_bounds__(256, 2)
void edm_main(const __bf16* __restrict__ xb, const float* __restrict__ sq,
              float* __restrict__ out) {
    __shared__ __align__(16) __bf16 As[128 * DD];   // 32 KB, swizzled
    __shared__ __align__(16) __bf16 Bs[128 * DD];   // 32 KB, swizzled

    const int t    = threadIdx.x;
    const int wave = t >> 6;
    const int lane = t & 63;
    const int lm   = lane & 15;
    const int q    = lane >> 4;

    const int jt = blockIdx.x;   // 0..15
    const int it = blockIdx.y;   // 0..15
    const int b  = blockIdx.z;   // 0..3

    const __bf16* xbb = xb + (size_t)b * NN * DD;
    const float*  sqb = sq + (size_t)b * NN;

    // stage A (rows it*128..) and B (rows jt*128..): 16-B chunks, chunk c of
    // row r lands at physical chunk (c ^ (r&15)) -> ds reads are ~2-way only.
    #pragma unroll
    for (int iter = 0; iter < 8; ++iter) {
        const int idx = t + iter * 256;     // 0..2047
        const int row = idx >> 4;
        const int c   = idx & 15;
        const int dst = row * DD + ((c ^ (row & 15)) * 8);
        bf16x8 va = *(const bf16x8*)(xbb + (size_t)(it * 128 + row) * DD + c * 8);
        *(bf16x8*)&As[dst] = va;
        bf16x8 vb = *(const bf16x8*)(xbb + (size_t)(jt * 128 + row) * DD + c * 8);
        *(bf16x8*)&Bs[dst] = vb;
    }
    __syncthreads();

    const int wm = (wave >> 1) * 64;
    const int wn = (wave & 1) * 64;

    f32x4 acc[4][4] = {};
    #pragma unroll
    for (int ks = 0; ks < 4; ++ks) {
        const int cc = ks * 4 + q;          // logical chunk for this lane
        bf16x8 a[4], bb[4];
        #pragma unroll
        for (int mf = 0; mf < 4; ++mf) {
            const int R = wm + mf * 16 + lm;          // R&15 == lm
            a[mf] = *(const bf16x8*)&As[R * DD + ((cc ^ lm) * 8)];
        }
        #pragma unroll
        for (int nf = 0; nf < 4; ++nf) {
            const int R = wn + nf * 16 + lm;
            bb[nf] = *(const bf16x8*)&Bs[R * DD + ((cc ^ lm) * 8)];
        }
        #pragma unroll
        for (int mf = 0; mf < 4; ++mf)
            #pragma unroll
            for (int nf = 0; nf < 4; ++nf)
                acc[mf][nf] = __builtin_amdgcn_mfma_f32_16x16x32_bf16(
                    a[mf], bb[nf], acc[mf][nf], 0, 0, 0);
    }

    // epilogue: d = sqrt(max(sqi+sqj-2c,0)+eps); stores are full 64-B lines
    const int i0 = it * 128 + wm;
    const int j0 = jt * 128 + wn;
    f32x4 sqi[4];
    float sqj[4];
    #pragma unroll
    for (int mf = 0; mf < 4; ++mf)
        sqi[mf] = *(const f32x4*)(sqb + i0 + mf * 16 + q * 4);
    #pragma unroll
    for (int nf = 0; nf < 4; ++nf)
        sqj[nf] = sqb[j0 + nf * 16 + lm];

    float* op = out + ((size_t)b * NN + i0) * NN + j0;
    #pragma unroll
    for (int mf = 0; mf < 4; ++mf) {
        #pragma unroll
        for (int r = 0; r < 4; ++r) {
            const int row = mf * 16 + q * 4 + r;
            #pragma unroll
            for (int nf = 0; nf < 4; ++nf) {
                float d2 = sqi[mf][r] + sqj[nf] - 2.0f * acc[mf][nf][r];
                d2 = fmaxf(d2, 0.0f);
                op[(size_t)row * NN + nf * 16 + lm] = sqrtf(d2 + 1e-7f);
            }
        }
    }
}

extern "C" void kernel_launch(void* const* d_in, const int* in_sizes, int n_in,
                              void* d_out, int out_size, void* d_ws, size_t ws_size,
                              hipStream_t stream) {
    const float* x = (const float*)d_in[0];
    float* out = (float*)d_out;
    __bf16* xb = (__bf16*)d_ws;                            // 2 MB bf16 copy
    float*  sq = (float*)((char*)d_ws + (size_t)4 * NN * DD * 2);  // 32 KB

    prep_kernel<<<dim3(4 * NN / 4), dim3(256), 0, stream>>>(x, xb, sq);
    edm_main<<<dim3(16, 16, 4), dim3(256), 0, stream>>>(xb, sq, out);
}

// Round 4
// 86.999 us; speedup vs baseline: 1.2778x; 1.0084x over previous
//
#include <hip/hip_runtime.h>
#include <hip/hip_bf16.h>

typedef __attribute__((ext_vector_type(8))) __bf16 bf16x8;
typedef __attribute__((ext_vector_type(2))) __bf16 bf16x2;
typedef __attribute__((ext_vector_type(4))) float  f32x4;

constexpr int NN = 2048;   // points per batch
constexpr int DD = 128;    // dim

// ---- pre-pass: bf16-convert x into ws and compute sq from the ROUNDED values
__global__ __launch_bounds__(256, 4)
void prep_kernel(const float* __restrict__ x, __bf16* __restrict__ xb,
                 float* __restrict__ sq) {
    const int lane = threadIdx.x & 63;
    const int row  = blockIdx.x * 4 + (threadIdx.x >> 6);   // 0..8191
    const float2 v = *(const float2*)(x + (size_t)row * DD + lane * 2);
    const __bf16 b0 = (__bf16)v.x;
    const __bf16 b1 = (__bf16)v.y;
    bf16x2 w; w[0] = b0; w[1] = b1;
    *(bf16x2*)(xb + (size_t)row * DD + lane * 2) = w;
    const float f0 = (float)b0, f1 = (float)b1;
    float s = f0 * f0 + f1 * f1;
    #pragma unroll
    for (int m = 1; m < 64; m <<= 1) s += __shfl_xor(s, m, 64);
    if (lane == 0) sq[row] = s;
}

// ---- main: 128x128 tile per block. A-operand = J-tile rows, B-operand =
// I-tile rows, so the MFMA C/D layout gives each lane 4 CONSECUTIVE output
// columns -> register-only dwordx4 stores. One barrier, no LDS epilogue.
__global__ __launch_bounds__(256, 2)
void edm_main(const __bf16* __restrict__ xb, const float* __restrict__ sq,
              float* __restrict__ out) {
    __shared__ __align__(16) __bf16 Ls[128 * DD];   // 32 KB, J-tile (A-operand)
    __shared__ __align__(16) __bf16 Rs[128 * DD];   // 32 KB, I-tile (B-operand)

    const int t    = threadIdx.x;
    const int wave = t >> 6;
    const int lane = t & 63;
    const int lm   = lane & 15;
    const int q    = lane >> 4;

    const int jt = blockIdx.x;   // 0..15
    const int it = blockIdx.y;   // 0..15
    const int b  = blockIdx.z;   // 0..3

    const __bf16* xbb = xb + (size_t)b * NN * DD;
    const float*  sqb = sq + (size_t)b * NN;

    // stage: 16-B chunks, chunk c of row r -> physical chunk (c ^ (r&15))
    #pragma unroll
    for (int iter = 0; iter < 8; ++iter) {
        const int idx = t + iter * 256;     // 0..2047
        const int row = idx >> 4;
        const int c   = idx & 15;
        const int dst = row * DD + ((c ^ (row & 15)) * 8);
        bf16x8 vl = *(const bf16x8*)(xbb + (size_t)(jt * 128 + row) * DD + c * 8);
        *(bf16x8*)&Ls[dst] = vl;
        bf16x8 vr = *(const bf16x8*)(xbb + (size_t)(it * 128 + row) * DD + c * 8);
        *(bf16x8*)&Rs[dst] = vr;
    }
    __syncthreads();

    const int wm = (wave >> 1) * 64;   // j-offset within tile
    const int wn = (wave & 1) * 64;    // i-offset within tile

    f32x4 acc[4][4] = {};
    #pragma unroll
    for (int ks = 0; ks < 4; ++ks) {
        const int cc = ks * 4 + q;
        bf16x8 a[4], bb[4];
        #pragma unroll
        for (int mf = 0; mf < 4; ++mf) {
            const int R = wm + mf * 16 + lm;          // R&15 == lm
            a[mf] = *(const bf16x8*)&Ls[R * DD + ((cc ^ lm) * 8)];
        }
        #pragma unroll
        for (int nf = 0; nf < 4; ++nf) {
            const int R = wn + nf * 16 + lm;
            bb[nf] = *(const bf16x8*)&Rs[R * DD + ((cc ^ lm) * 8)];
        }
        #pragma unroll
        for (int mf = 0; mf < 4; ++mf)
            #pragma unroll
            for (int nf = 0; nf < 4; ++nf)
                acc[mf][nf] = __builtin_amdgcn_mfma_f32_16x16x32_bf16(
                    a[mf], bb[nf], acc[mf][nf], 0, 0, 0);
    }
    // acc[mf][nf][r] = dot(x[j0+wm+mf*16+q*4+r], x[i0+wn+nf*16+lm])

    const int i0 = it * 128;
    const int j0 = jt * 128;

    f32x4 sqj[4];   // 4 consecutive j per lane, per mf
    float sqi[4];   // fixed i per lane, per nf
    #pragma unroll
    for (int mf = 0; mf < 4; ++mf)
        sqj[mf] = *(const f32x4*)(sqb + j0 + wm + mf * 16 + q * 4);
    #pragma unroll
    for (int nf = 0; nf < 4; ++nf)
        sqi[nf] = sqb[i0 + wn + nf * 16 + lm];

    #pragma unroll
    for (int nf = 0; nf < 4; ++nf) {
        float* op = out + ((size_t)b * NN + i0 + wn + nf * 16 + lm) * NN + j0 + wm;
        #pragma unroll
        for (int mf = 0; mf < 4; ++mf) {
            f32x4 v;
            #pragma unroll
            for (int r = 0; r < 4; ++r) {
                float d2 = sqi[nf] + sqj[mf][r] - 2.0f * acc[mf][nf][r];
                d2 = fmaxf(d2, 0.0f);
                v[r] = sqrtf(d2 + 1e-7f);
            }
            *(f32x4*)(op + mf * 16 + q * 4) = v;
        }
    }
}

extern "C" void kernel_launch(void* const* d_in, const int* in_sizes, int n_in,
                              void* d_out, int out_size, void* d_ws, size_t ws_size,
                              hipStream_t stream) {
    const float* x = (const float*)d_in[0];
    float* out = (float*)d_out;
    __bf16* xb = (__bf16*)d_ws;                            // 2 MB bf16 copy
    float*  sq = (float*)((char*)d_ws + (size_t)4 * NN * DD * 2);  // 32 KB

    prep_kernel<<<dim3(4 * NN / 4), dim3(256), 0, stream>>>(x, xb, sq);
    edm_main<<<dim3(16, 16, 4), dim3(256), 0, stream>>>(xb, sq, out);
}